// Round 2
// baseline (351.035 us; speedup 1.0000x reference)
//
#include <hip/hip_runtime.h>

#define VOCAB   100000
#define EMB     128
#define CLASSES 1000
#define BATCH   16384
#define SEQLEN  200

typedef short bf16x8 __attribute__((ext_vector_type(8)));
typedef float f32x4  __attribute__((ext_vector_type(4)));

__device__ __forceinline__ unsigned short f32_to_bf16(float f) {
    unsigned int u = __builtin_bit_cast(unsigned int, f);
    u += 0x7fffu + ((u >> 16) & 1u);   // round-to-nearest-even
    return (unsigned short)(u >> 16);
}

// Kernel 0: fc_w f32 [CLASSES, EMB] -> bf16 (for MFMA).  128000 elts.
__global__ __launch_bounds__(256) void convert_w(const float* __restrict__ w,
                                                 unsigned short* __restrict__ wb) {
    const int i = (blockIdx.x * 256 + threadIdx.x) * 4;   // 125 blocks * 256 * 4 = 128000
    float4 v = *(const float4*)(w + i);
    ushort4 o;
    o.x = f32_to_bf16(v.x); o.y = f32_to_bf16(v.y);
    o.z = f32_to_bf16(v.z); o.w = f32_to_bf16(v.w);
    *(ushort4*)(wb + i) = o;
}

// Kernel 1: masked embedding-bag sum pool (f32 gather, fp32 accumulate,
// bf16 pooled row out).  One wave per bag.  Tokens processed in pairs:
// lanes 0-31 handle token 2q (dims 4*(lane&31)..+3), lanes 32-63 token 2q+1
// -> one 16B/lane load = 1 KB = two full 512B rows per instruction.
__global__ __launch_bounds__(256) void bag_pool(const int* __restrict__ seq,
                                                const float* __restrict__ emb,
                                                unsigned short* __restrict__ pooled) {
    const int lane = threadIdx.x & 63;
    const int wid  = threadIdx.x >> 6;
    const int b    = blockIdx.x * 4 + wid;

    const int* srow = seq + (long)b * SEQLEN;
    int ids0 = srow[lane];
    int ids1 = srow[lane + 64];
    int ids2 = srow[lane + 128];
    int ids3 = (lane < SEQLEN - 192) ? srow[lane + 192] : 0;

    const int half = lane >> 5;          // which token of the pair this lane serves
    const int dsub = (lane & 31) * 4;    // first of 4 dims this lane accumulates

    float4 acc = {0.f, 0.f, 0.f, 0.f};

#define PAIR_BODY(IDS, Q)                                                   \
    {                                                                       \
        int tok = __shfl((IDS), 2 * (Q) + half);                            \
        if (tok != 0) {                                                     \
            float4 v = *(const float4*)(emb + (long)tok * EMB + dsub);      \
            acc.x += v.x; acc.y += v.y; acc.z += v.z; acc.w += v.w;         \
        }                                                                   \
    }

#pragma unroll 8
    for (int q = 0; q < 32; ++q) PAIR_BODY(ids0, q)
#pragma unroll 8
    for (int q = 0; q < 32; ++q) PAIR_BODY(ids1, q)
#pragma unroll 8
    for (int q = 0; q < 32; ++q) PAIR_BODY(ids2, q)
#pragma unroll
    for (int q = 0; q < 4; ++q)  PAIR_BODY(ids3, q)
#undef PAIR_BODY

    // Combine the two half-wave token streams (same dims, different tokens).
    acc.x += __shfl_xor(acc.x, 32);
    acc.y += __shfl_xor(acc.y, 32);
    acc.z += __shfl_xor(acc.z, 32);
    acc.w += __shfl_xor(acc.w, 32);

    if (lane < 32) {
        uint2 o;
        o.x = (unsigned int)f32_to_bf16(acc.x) | ((unsigned int)f32_to_bf16(acc.y) << 16);
        o.y = (unsigned int)f32_to_bf16(acc.z) | ((unsigned int)f32_to_bf16(acc.w) << 16);
        *(uint2*)(pooled + (long)b * EMB + dsub) = o;
    }
}

// Kernel 2: out[b,c] = pooled[b,:] . fc_w[c,:] + fc_b[c]   (NT GEMM, K=128)
// LDS-free MFMA: A-fragments (16 rows x K=128) live in registers across 7
// n-tiles; W-fragments stream through L1/L2 (fcw_bf16 = 256 KB, fully cached).
// fp32 accumulate + f32 bias + f32 store.
__global__ __launch_bounds__(256) void bow_gemm(const unsigned short* __restrict__ pooled,
                                                const unsigned short* __restrict__ fcw,
                                                const float* __restrict__ fcb,
                                                float* __restrict__ out) {
    const int lane = threadIdx.x & 63;
    const int wid  = threadIdx.x >> 6;
    const int m0   = blockIdx.x * 64 + wid * 16;     // 16 bag-rows per wave
    const int mrow = m0 + (lane & 15);
    const int koff = (lane >> 4) * 8;                // A[m=lane&15][k=quad*8+j]

    const unsigned short* ar = pooled + (long)mrow * EMB + koff;
    bf16x8 a0 = *(const bf16x8*)(ar + 0 * 32);
    bf16x8 a1 = *(const bf16x8*)(ar + 1 * 32);
    bf16x8 a2 = *(const bf16x8*)(ar + 2 * 32);
    bf16x8 a3 = *(const bf16x8*)(ar + 3 * 32);

#pragma unroll
    for (int i = 0; i < 7; ++i) {
        const int n0  = (blockIdx.y * 7 + i) * 16;   // 63 tiles of 16 cover 1000 (pad 1008)
        const int col = n0 + (lane & 15);
        const int cw  = (col < CLASSES) ? col : 0;   // clamp loads, guard stores

        const unsigned short* wr = fcw + (long)cw * EMB + koff;
        bf16x8 w0 = *(const bf16x8*)(wr + 0 * 32);
        bf16x8 w1 = *(const bf16x8*)(wr + 1 * 32);
        bf16x8 w2 = *(const bf16x8*)(wr + 2 * 32);
        bf16x8 w3 = *(const bf16x8*)(wr + 3 * 32);

        f32x4 acc = {0.f, 0.f, 0.f, 0.f};
        acc = __builtin_amdgcn_mfma_f32_16x16x32_bf16(a0, w0, acc, 0, 0, 0);
        acc = __builtin_amdgcn_mfma_f32_16x16x32_bf16(a1, w1, acc, 0, 0, 0);
        acc = __builtin_amdgcn_mfma_f32_16x16x32_bf16(a2, w2, acc, 0, 0, 0);
        acc = __builtin_amdgcn_mfma_f32_16x16x32_bf16(a3, w3, acc, 0, 0, 0);

        if (col < CLASSES) {
            const float bias = fcb[col];
#pragma unroll
            for (int r = 0; r < 4; ++r) {
                const int row = m0 + (lane >> 4) * 4 + r;   // C/D: col=lane&15, row=quad*4+r
                out[(long)row * CLASSES + col] = acc[r] + bias;
            }
        }
    }
}

extern "C" void kernel_launch(void* const* d_in, const int* in_sizes, int n_in,
                              void* d_out, int out_size, void* d_ws, size_t ws_size,
                              hipStream_t stream) {
    const int*   seq = (const int*)d_in[0];
    const float* emb = (const float*)d_in[1];   // f32 [VOCAB, EMB]
    const float* fcw = (const float*)d_in[2];   // f32 [CLASSES, EMB]
    const float* fcb = (const float*)d_in[3];   // f32 [CLASSES]
    float*       out = (float*)d_out;           // f32 [BATCH, CLASSES]

    unsigned short* pooled   = (unsigned short*)d_ws;            // bf16 [BATCH, EMB]  (4 MB)
    unsigned short* fcw_bf16 = pooled + (long)BATCH * EMB;       // bf16 [CLASSES,EMB] (256 KB)

    convert_w<<<125, 256, 0, stream>>>(fcw, fcw_bf16);
    bag_pool<<<BATCH / 4, 256, 0, stream>>>(seq, emb, pooled);
    bow_gemm<<<dim3(BATCH / 64, 9), 256, 0, stream>>>(pooled, fcw_bf16, fcb, out);
}

// Round 3
// 249.480 us; speedup vs baseline: 1.4071x; 1.4071x over previous
//
#include <hip/hip_runtime.h>

#define VOCAB   100000
#define EMB     128
#define CLASSES 1000
#define BATCH   16384
#define SEQLEN  200

typedef short bf16x8 __attribute__((ext_vector_type(8)));
typedef float f32x4  __attribute__((ext_vector_type(4)));

__device__ __forceinline__ unsigned short f32_to_bf16(float f) {
    unsigned int u = __builtin_bit_cast(unsigned int, f);
    u += 0x7fffu + ((u >> 16) & 1u);   // round-to-nearest-even
    return (unsigned short)(u >> 16);
}
__device__ __forceinline__ float bf_lo(unsigned int p) { return __builtin_bit_cast(float, p << 16); }
__device__ __forceinline__ float bf_hi(unsigned int p) { return __builtin_bit_cast(float, p & 0xffff0000u); }

// fc_w f32 [CLASSES, EMB] -> bf16.  128000 elts, 4/thread.
__global__ __launch_bounds__(256) void convert_w(const float* __restrict__ w,
                                                 unsigned short* __restrict__ wb) {
    const int i = (blockIdx.x * 256 + threadIdx.x) * 4;   // 125 blocks
    float4 v = *(const float4*)(w + i);
    ushort4 o;
    o.x = f32_to_bf16(v.x); o.y = f32_to_bf16(v.y);
    o.z = f32_to_bf16(v.z); o.w = f32_to_bf16(v.w);
    *(ushort4*)(wb + i) = o;
}

// emb f32 [VOCAB, EMB] -> bf16.  12.8M elts, 8/thread (16B read x2, 16B write).
__global__ __launch_bounds__(256) void convert_emb(const float* __restrict__ e,
                                                   unsigned short* __restrict__ eb) {
    const long i = ((long)blockIdx.x * 256 + threadIdx.x) * 8;   // 6250 blocks
    float4 v0 = *(const float4*)(e + i);
    float4 v1 = *(const float4*)(e + i + 4);
    uint4 o;
    o.x = (unsigned int)f32_to_bf16(v0.x) | ((unsigned int)f32_to_bf16(v0.y) << 16);
    o.y = (unsigned int)f32_to_bf16(v0.z) | ((unsigned int)f32_to_bf16(v0.w) << 16);
    o.z = (unsigned int)f32_to_bf16(v1.x) | ((unsigned int)f32_to_bf16(v1.y) << 16);
    o.w = (unsigned int)f32_to_bf16(v1.z) | ((unsigned int)f32_to_bf16(v1.w) << 16);
    *(uint4*)(eb + i) = o;
}

// Masked embedding-bag sum pool over the bf16 table.  One wave per bag.
// 4 tokens per iteration: quad = lane>>4 serves token 4q+quad, lane&15 serves
// dims 8*(lane&15)..+7 -> 16B/lane load = 1 KB = four full 256B rows per
// instruction.  fp32 accumulate, shfl_xor(16/32) combine, bf16 row out.
__global__ __launch_bounds__(256) void bag_pool_bf16(const int* __restrict__ seq,
                                                     const unsigned short* __restrict__ emb,
                                                     unsigned short* __restrict__ pooled) {
    const int lane = threadIdx.x & 63;
    const int wid  = threadIdx.x >> 6;
    const int b    = blockIdx.x * 4 + wid;

    const int* srow = seq + (long)b * SEQLEN;
    int ids0 = srow[lane];
    int ids1 = srow[lane + 64];
    int ids2 = srow[lane + 128];
    int ids3 = (lane < 8) ? srow[lane + 192] : 0;

    const int quad = lane >> 4;
    const int dsub = (lane & 15) * 8;

    float a0 = 0.f, a1 = 0.f, a2 = 0.f, a3 = 0.f;
    float a4 = 0.f, a5 = 0.f, a6 = 0.f, a7 = 0.f;

#define GBODY(IDS, QL)                                                        \
    {                                                                         \
        int tok = __shfl((IDS), 4 * (QL) + quad);                             \
        if (tok != 0) {                                                       \
            uint4 v = *(const uint4*)(emb + (long)tok * EMB + dsub);          \
            a0 += bf_lo(v.x); a1 += bf_hi(v.x);                               \
            a2 += bf_lo(v.y); a3 += bf_hi(v.y);                               \
            a4 += bf_lo(v.z); a5 += bf_hi(v.z);                               \
            a6 += bf_lo(v.w); a7 += bf_hi(v.w);                               \
        }                                                                     \
    }

#pragma unroll 8
    for (int q = 0; q < 16; ++q) GBODY(ids0, q)   // tokens   0..63
#pragma unroll 8
    for (int q = 0; q < 16; ++q) GBODY(ids1, q)   // tokens  64..127
#pragma unroll 8
    for (int q = 0; q < 16; ++q) GBODY(ids2, q)   // tokens 128..191
#pragma unroll
    for (int q = 0; q < 2; ++q)  GBODY(ids3, q)   // tokens 192..199
#undef GBODY

    // Combine the 4 token streams (quads hold same dims, different tokens).
    a0 += __shfl_xor(a0, 16); a1 += __shfl_xor(a1, 16);
    a2 += __shfl_xor(a2, 16); a3 += __shfl_xor(a3, 16);
    a4 += __shfl_xor(a4, 16); a5 += __shfl_xor(a5, 16);
    a6 += __shfl_xor(a6, 16); a7 += __shfl_xor(a7, 16);
    a0 += __shfl_xor(a0, 32); a1 += __shfl_xor(a1, 32);
    a2 += __shfl_xor(a2, 32); a3 += __shfl_xor(a3, 32);
    a4 += __shfl_xor(a4, 32); a5 += __shfl_xor(a5, 32);
    a6 += __shfl_xor(a6, 32); a7 += __shfl_xor(a7, 32);

    if (lane < 16) {
        uint4 o;
        o.x = (unsigned int)f32_to_bf16(a0) | ((unsigned int)f32_to_bf16(a1) << 16);
        o.y = (unsigned int)f32_to_bf16(a2) | ((unsigned int)f32_to_bf16(a3) << 16);
        o.z = (unsigned int)f32_to_bf16(a4) | ((unsigned int)f32_to_bf16(a5) << 16);
        o.w = (unsigned int)f32_to_bf16(a6) | ((unsigned int)f32_to_bf16(a7) << 16);
        *(uint4*)(pooled + (long)b * EMB + dsub) = o;
    }
}

// Fallback f32-gather pool (used only if workspace can't hold the bf16 table).
__global__ __launch_bounds__(256) void bag_pool_f32(const int* __restrict__ seq,
                                                    const float* __restrict__ emb,
                                                    unsigned short* __restrict__ pooled) {
    const int lane = threadIdx.x & 63;
    const int wid  = threadIdx.x >> 6;
    const int b    = blockIdx.x * 4 + wid;
    const int* srow = seq + (long)b * SEQLEN;
    int ids0 = srow[lane];
    int ids1 = srow[lane + 64];
    int ids2 = srow[lane + 128];
    int ids3 = (lane < 8) ? srow[lane + 192] : 0;
    const int half = lane >> 5;
    const int dsub = (lane & 31) * 4;
    float4 acc = {0.f, 0.f, 0.f, 0.f};
#define PAIR_BODY(IDS, Q)                                                   \
    {                                                                       \
        int tok = __shfl((IDS), 2 * (Q) + half);                            \
        if (tok != 0) {                                                     \
            float4 v = *(const float4*)(emb + (long)tok * EMB + dsub);      \
            acc.x += v.x; acc.y += v.y; acc.z += v.z; acc.w += v.w;         \
        }                                                                   \
    }
#pragma unroll 8
    for (int q = 0; q < 32; ++q) PAIR_BODY(ids0, q)
#pragma unroll 8
    for (int q = 0; q < 32; ++q) PAIR_BODY(ids1, q)
#pragma unroll 8
    for (int q = 0; q < 32; ++q) PAIR_BODY(ids2, q)
#pragma unroll
    for (int q = 0; q < 4; ++q)  PAIR_BODY(ids3, q)
#undef PAIR_BODY
    acc.x += __shfl_xor(acc.x, 32);
    acc.y += __shfl_xor(acc.y, 32);
    acc.z += __shfl_xor(acc.z, 32);
    acc.w += __shfl_xor(acc.w, 32);
    if (lane < 32) {
        uint2 o;
        o.x = (unsigned int)f32_to_bf16(acc.x) | ((unsigned int)f32_to_bf16(acc.y) << 16);
        o.y = (unsigned int)f32_to_bf16(acc.z) | ((unsigned int)f32_to_bf16(acc.w) << 16);
        *(uint2*)(pooled + (long)b * EMB + dsub) = o;
    }
}

// out[b,c] = pooled[b,:] . fc_w[c,:] + fc_b[c]   (NT GEMM, K=128, MFMA)
__global__ __launch_bounds__(256) void bow_gemm(const unsigned short* __restrict__ pooled,
                                                const unsigned short* __restrict__ fcw,
                                                const float* __restrict__ fcb,
                                                float* __restrict__ out) {
    const int lane = threadIdx.x & 63;
    const int wid  = threadIdx.x >> 6;
    const int m0   = blockIdx.x * 64 + wid * 16;
    const int mrow = m0 + (lane & 15);
    const int koff = (lane >> 4) * 8;

    const unsigned short* ar = pooled + (long)mrow * EMB + koff;
    bf16x8 a0 = *(const bf16x8*)(ar + 0 * 32);
    bf16x8 a1 = *(const bf16x8*)(ar + 1 * 32);
    bf16x8 a2 = *(const bf16x8*)(ar + 2 * 32);
    bf16x8 a3 = *(const bf16x8*)(ar + 3 * 32);

#pragma unroll
    for (int i = 0; i < 7; ++i) {
        const int n0  = (blockIdx.y * 7 + i) * 16;
        const int col = n0 + (lane & 15);
        const int cw  = (col < CLASSES) ? col : 0;

        const unsigned short* wr = fcw + (long)cw * EMB + koff;
        bf16x8 w0 = *(const bf16x8*)(wr + 0 * 32);
        bf16x8 w1 = *(const bf16x8*)(wr + 1 * 32);
        bf16x8 w2 = *(const bf16x8*)(wr + 2 * 32);
        bf16x8 w3 = *(const bf16x8*)(wr + 3 * 32);

        f32x4 acc = {0.f, 0.f, 0.f, 0.f};
        acc = __builtin_amdgcn_mfma_f32_16x16x32_bf16(a0, w0, acc, 0, 0, 0);
        acc = __builtin_amdgcn_mfma_f32_16x16x32_bf16(a1, w1, acc, 0, 0, 0);
        acc = __builtin_amdgcn_mfma_f32_16x16x32_bf16(a2, w2, acc, 0, 0, 0);
        acc = __builtin_amdgcn_mfma_f32_16x16x32_bf16(a3, w3, acc, 0, 0, 0);

        if (col < CLASSES) {
            const float bias = fcb[col];
#pragma unroll
            for (int r = 0; r < 4; ++r) {
                const int row = m0 + (lane >> 4) * 4 + r;   // C/D: col=lane&15, row=quad*4+r
                out[(long)row * CLASSES + col] = acc[r] + bias;
            }
        }
    }
}

extern "C" void kernel_launch(void* const* d_in, const int* in_sizes, int n_in,
                              void* d_out, int out_size, void* d_ws, size_t ws_size,
                              hipStream_t stream) {
    const int*   seq = (const int*)d_in[0];
    const float* emb = (const float*)d_in[1];   // f32 [VOCAB, EMB]
    const float* fcw = (const float*)d_in[2];   // f32 [CLASSES, EMB]
    const float* fcb = (const float*)d_in[3];   // f32 [CLASSES]
    float*       out = (float*)d_out;           // f32 [BATCH, CLASSES]

    unsigned short* pooled   = (unsigned short*)d_ws;            // bf16 [BATCH, EMB]    4 MB
    unsigned short* fcw_bf16 = pooled + (long)BATCH * EMB;       // bf16 [CLASSES, EMB]  250 KB
    unsigned short* emb_bf16 = fcw_bf16 + (long)CLASSES * EMB;   // bf16 [VOCAB, EMB]    25.6 MB

    const size_t need = ((size_t)BATCH * EMB + (size_t)CLASSES * EMB + (size_t)VOCAB * EMB) * 2;

    convert_w<<<125, 256, 0, stream>>>(fcw, fcw_bf16);
    if (ws_size >= need) {
        convert_emb<<<6250, 256, 0, stream>>>(emb, emb_bf16);
        bag_pool_bf16<<<BATCH / 4, 256, 0, stream>>>(seq, emb_bf16, pooled);
    } else {
        bag_pool_f32<<<BATCH / 4, 256, 0, stream>>>(seq, emb, pooled);
    }
    bow_gemm<<<dim3(BATCH / 64, 9), 256, 0, stream>>>(pooled, fcw_bf16, fcb, out);
}

// Round 4
// 241.738 us; speedup vs baseline: 1.4521x; 1.0320x over previous
//
#include <hip/hip_runtime.h>

#define VOCAB   100000
#define EMB     128
#define CLASSES 1000
#define BATCH   16384
#define SEQLEN  200

typedef short bf16x8 __attribute__((ext_vector_type(8)));
typedef float f32x4  __attribute__((ext_vector_type(4)));

__device__ __forceinline__ unsigned short f32_to_bf16(float f) {
    unsigned int u = __builtin_bit_cast(unsigned int, f);
    u += 0x7fffu + ((u >> 16) & 1u);   // round-to-nearest-even
    return (unsigned short)(u >> 16);
}
__device__ __forceinline__ float bf_lo(unsigned int p) { return __builtin_bit_cast(float, p << 16); }
__device__ __forceinline__ float bf_hi(unsigned int p) { return __builtin_bit_cast(float, p & 0xffff0000u); }

// One dispatch converts BOTH f32 tables to bf16: blocks [0,6250) handle emb
// (12.8M elts, 8/thread exactly), blocks [6250,6313) handle fc_w (128000 elts).
__global__ __launch_bounds__(256) void convert_all(const float* __restrict__ emb,
                                                   const float* __restrict__ fcw,
                                                   unsigned short* __restrict__ eb,
                                                   unsigned short* __restrict__ wb) {
    const float* src;
    unsigned short* dst;
    long i;
    if (blockIdx.x < 6250) {
        i = ((long)blockIdx.x * 256 + threadIdx.x) * 8;
        src = emb; dst = eb;
    } else {
        i = (((long)blockIdx.x - 6250) * 256 + threadIdx.x) * 8;
        if (i >= (long)CLASSES * EMB) return;
        src = fcw; dst = wb;
    }
    float4 v0 = *(const float4*)(src + i);
    float4 v1 = *(const float4*)(src + i + 4);
    uint4 o;
    o.x = (unsigned int)f32_to_bf16(v0.x) | ((unsigned int)f32_to_bf16(v0.y) << 16);
    o.y = (unsigned int)f32_to_bf16(v0.z) | ((unsigned int)f32_to_bf16(v0.w) << 16);
    o.z = (unsigned int)f32_to_bf16(v1.x) | ((unsigned int)f32_to_bf16(v1.y) << 16);
    o.w = (unsigned int)f32_to_bf16(v1.z) | ((unsigned int)f32_to_bf16(v1.w) << 16);
    *(uint4*)(dst + i) = o;
}

// Masked embedding-bag sum pool over the bf16 table.  One wave per bag.
// 4 tokens/iteration: quad=lane>>4 serves token 4q+quad, lane&15 serves dims
// 8*(lane&15)..+7 -> 16B/lane = 1 KB = four full 256B rows per instruction.
// (UNCHANGED from round 3: measured 104 us, ~8.1 TB/s effective gather.)
__global__ __launch_bounds__(256) void bag_pool_bf16(const int* __restrict__ seq,
                                                     const unsigned short* __restrict__ emb,
                                                     unsigned short* __restrict__ pooled) {
    const int lane = threadIdx.x & 63;
    const int wid  = threadIdx.x >> 6;
    const int b    = blockIdx.x * 4 + wid;

    const int* srow = seq + (long)b * SEQLEN;
    int ids0 = srow[lane];
    int ids1 = srow[lane + 64];
    int ids2 = srow[lane + 128];
    int ids3 = (lane < 8) ? srow[lane + 192] : 0;

    const int quad = lane >> 4;
    const int dsub = (lane & 15) * 8;

    float a0 = 0.f, a1 = 0.f, a2 = 0.f, a3 = 0.f;
    float a4 = 0.f, a5 = 0.f, a6 = 0.f, a7 = 0.f;

#define GBODY(IDS, QL)                                                        \
    {                                                                         \
        int tok = __shfl((IDS), 4 * (QL) + quad);                             \
        if (tok != 0) {                                                       \
            uint4 v = *(const uint4*)(emb + (long)tok * EMB + dsub);          \
            a0 += bf_lo(v.x); a1 += bf_hi(v.x);                               \
            a2 += bf_lo(v.y); a3 += bf_hi(v.y);                               \
            a4 += bf_lo(v.z); a5 += bf_hi(v.z);                               \
            a6 += bf_lo(v.w); a7 += bf_hi(v.w);                               \
        }                                                                     \
    }

#pragma unroll 8
    for (int q = 0; q < 16; ++q) GBODY(ids0, q)
#pragma unroll 8
    for (int q = 0; q < 16; ++q) GBODY(ids1, q)
#pragma unroll 8
    for (int q = 0; q < 16; ++q) GBODY(ids2, q)
#pragma unroll
    for (int q = 0; q < 2; ++q)  GBODY(ids3, q)
#undef GBODY

    a0 += __shfl_xor(a0, 16); a1 += __shfl_xor(a1, 16);
    a2 += __shfl_xor(a2, 16); a3 += __shfl_xor(a3, 16);
    a4 += __shfl_xor(a4, 16); a5 += __shfl_xor(a5, 16);
    a6 += __shfl_xor(a6, 16); a7 += __shfl_xor(a7, 16);
    a0 += __shfl_xor(a0, 32); a1 += __shfl_xor(a1, 32);
    a2 += __shfl_xor(a2, 32); a3 += __shfl_xor(a3, 32);
    a4 += __shfl_xor(a4, 32); a5 += __shfl_xor(a5, 32);
    a6 += __shfl_xor(a6, 32); a7 += __shfl_xor(a7, 32);

    if (lane < 16) {
        uint4 o;
        o.x = (unsigned int)f32_to_bf16(a0) | ((unsigned int)f32_to_bf16(a1) << 16);
        o.y = (unsigned int)f32_to_bf16(a2) | ((unsigned int)f32_to_bf16(a3) << 16);
        o.z = (unsigned int)f32_to_bf16(a4) | ((unsigned int)f32_to_bf16(a5) << 16);
        o.w = (unsigned int)f32_to_bf16(a6) | ((unsigned int)f32_to_bf16(a7) << 16);
        *(uint4*)(pooled + (long)b * EMB + dsub) = o;
    }
}

// Fallback f32-gather pool (only if workspace can't hold the bf16 table).
__global__ __launch_bounds__(256) void bag_pool_f32(const int* __restrict__ seq,
                                                    const float* __restrict__ emb,
                                                    unsigned short* __restrict__ pooled) {
    const int lane = threadIdx.x & 63;
    const int wid  = threadIdx.x >> 6;
    const int b    = blockIdx.x * 4 + wid;
    const int* srow = seq + (long)b * SEQLEN;
    int ids0 = srow[lane];
    int ids1 = srow[lane + 64];
    int ids2 = srow[lane + 128];
    int ids3 = (lane < 8) ? srow[lane + 192] : 0;
    const int half = lane >> 5;
    const int dsub = (lane & 31) * 4;
    float4 acc = {0.f, 0.f, 0.f, 0.f};
#define PAIR_BODY(IDS, Q)                                                   \
    {                                                                       \
        int tok = __shfl((IDS), 2 * (Q) + half);                            \
        if (tok != 0) {                                                     \
            float4 v = *(const float4*)(emb + (long)tok * EMB + dsub);      \
            acc.x += v.x; acc.y += v.y; acc.z += v.z; acc.w += v.w;         \
        }                                                                   \
    }
#pragma unroll 8
    for (int q = 0; q < 32; ++q) PAIR_BODY(ids0, q)
#pragma unroll 8
    for (int q = 0; q < 32; ++q) PAIR_BODY(ids1, q)
#pragma unroll 8
    for (int q = 0; q < 32; ++q) PAIR_BODY(ids2, q)
#pragma unroll
    for (int q = 0; q < 4; ++q)  PAIR_BODY(ids3, q)
#undef PAIR_BODY
    acc.x += __shfl_xor(acc.x, 32);
    acc.y += __shfl_xor(acc.y, 32);
    acc.z += __shfl_xor(acc.z, 32);
    acc.w += __shfl_xor(acc.w, 32);
    if (lane < 32) {
        uint2 o;
        o.x = (unsigned int)f32_to_bf16(acc.x) | ((unsigned int)f32_to_bf16(acc.y) << 16);
        o.y = (unsigned int)f32_to_bf16(acc.z) | ((unsigned int)f32_to_bf16(acc.w) << 16);
        *(uint2*)(pooled + (long)b * EMB + dsub) = o;
    }
}

// out[b,c] = pooled[b,:] . fc_w[c,:] + fc_b[c]   (NT GEMM, K=128, MFMA)
// v2: A-frag (16 rows x K=128) loaded ONCE per wave, reused across 21 n-tiles.
// No tile-loop unroll (v1's full unroll hoisted 28 W-frags -> VGPR cliff);
// instead a 2-stage software pipeline: prefetch W of tile i+1 while MFMA on
// tile i.  Grid (256,3): 768 blocks = 3/CU, ~12 waves/CU.
__global__ __launch_bounds__(256) void bow_gemm(const unsigned short* __restrict__ pooled,
                                                const unsigned short* __restrict__ fcw,
                                                const float* __restrict__ fcb,
                                                float* __restrict__ out) {
    const int lane = threadIdx.x & 63;
    const int wid  = threadIdx.x >> 6;
    const int quad = lane >> 4;
    const int m0   = blockIdx.x * 64 + wid * 16;
    const int mrow = m0 + (lane & 15);
    const int koff = quad * 8;                   // A[m=lane&15][k=quad*8+j]

    const unsigned short* ar = pooled + (long)mrow * EMB + koff;
    bf16x8 a0 = *(const bf16x8*)(ar + 0 * 32);
    bf16x8 a1 = *(const bf16x8*)(ar + 1 * 32);
    bf16x8 a2 = *(const bf16x8*)(ar + 2 * 32);
    bf16x8 a3 = *(const bf16x8*)(ar + 3 * 32);

    int ccur = (blockIdx.y * 21) * 16 + (lane & 15);   // 3 x 21 tiles cover 63
    const unsigned short* wr = fcw + (long)((ccur < CLASSES) ? ccur : 0) * EMB + koff;
    bf16x8 w0 = *(const bf16x8*)(wr + 0 * 32);
    bf16x8 w1 = *(const bf16x8*)(wr + 1 * 32);
    bf16x8 w2 = *(const bf16x8*)(wr + 2 * 32);
    bf16x8 w3 = *(const bf16x8*)(wr + 3 * 32);

#pragma unroll 1
    for (int i = 0; i < 21; ++i) {
        bf16x8 c0 = w0, c1 = w1, c2 = w2, c3 = w3;
        const int cc = ccur;
        if (i + 1 < 21) {                        // prefetch next tile's W-frag
            ccur += 16;
            const unsigned short* wn = fcw + (long)((ccur < CLASSES) ? ccur : 0) * EMB + koff;
            w0 = *(const bf16x8*)(wn + 0 * 32);
            w1 = *(const bf16x8*)(wn + 1 * 32);
            w2 = *(const bf16x8*)(wn + 2 * 32);
            w3 = *(const bf16x8*)(wn + 3 * 32);
        }
        f32x4 acc = {0.f, 0.f, 0.f, 0.f};
        acc = __builtin_amdgcn_mfma_f32_16x16x32_bf16(a0, c0, acc, 0, 0, 0);
        acc = __builtin_amdgcn_mfma_f32_16x16x32_bf16(a1, c1, acc, 0, 0, 0);
        acc = __builtin_amdgcn_mfma_f32_16x16x32_bf16(a2, c2, acc, 0, 0, 0);
        acc = __builtin_amdgcn_mfma_f32_16x16x32_bf16(a3, c3, acc, 0, 0, 0);

        if (cc < CLASSES) {
            const float bias = fcb[cc];
            float* orow = out + (long)(m0 + quad * 4) * CLASSES + cc;
#pragma unroll
            for (int r = 0; r < 4; ++r)          // C/D: col=lane&15, row=quad*4+r
                orow[(long)r * CLASSES] = acc[r] + bias;
        }
    }
}

extern "C" void kernel_launch(void* const* d_in, const int* in_sizes, int n_in,
                              void* d_out, int out_size, void* d_ws, size_t ws_size,
                              hipStream_t stream) {
    const int*   seq = (const int*)d_in[0];
    const float* emb = (const float*)d_in[1];   // f32 [VOCAB, EMB]
    const float* fcw = (const float*)d_in[2];   // f32 [CLASSES, EMB]
    const float* fcb = (const float*)d_in[3];   // f32 [CLASSES]
    float*       out = (float*)d_out;           // f32 [BATCH, CLASSES]

    unsigned short* pooled   = (unsigned short*)d_ws;            // bf16 [BATCH, EMB]    4 MB
    unsigned short* fcw_bf16 = pooled + (long)BATCH * EMB;       // bf16 [CLASSES, EMB]  250 KB
    unsigned short* emb_bf16 = fcw_bf16 + (long)CLASSES * EMB;   // bf16 [VOCAB, EMB]    25.6 MB

    const size_t need = ((size_t)BATCH * EMB + (size_t)CLASSES * EMB + (size_t)VOCAB * EMB) * 2;

    if (ws_size >= need) {
        convert_all<<<6313, 256, 0, stream>>>(emb, fcw, emb_bf16, fcw_bf16);
        bag_pool_bf16<<<BATCH / 4, 256, 0, stream>>>(seq, emb_bf16, pooled);
    } else {
        convert_all<<<6313, 256, 0, stream>>>(emb, fcw, emb_bf16, fcw_bf16);  // emb part unused
        bag_pool_f32<<<BATCH / 4, 256, 0, stream>>>(seq, emb, pooled);
    }
    bow_gemm<<<dim3(BATCH / 64, 3), 256, 0, stream>>>(pooled, fcw_bf16, fcb, out);
}